// Round 7
// baseline (17.274 us; speedup 1.0000x reference)
//
#include <hip/hip_runtime.h>
#include <math.h>

// SGO_Loss_Prod: B=16, N=256 atoms, K=16 ops, r=0.4.
// Min-image collapse (r<0.5): exactly/at-most one periodic shift can pass the
// mask -> direct minimum-image evaluation (validated bit-exact R1/R2).
// R7: ONE kernel node (two-node overhead ~10us was the floor: R2 vs R6
// identical at 14.7/14.8 despite 40% VALU cut). One block per (b,k) computes
// both identity and op sums locally (R4-validated), with R6's even/odd
// register-blocking (1 ds_read_b128 -> 2 evals) and 9-inst d-rint(d) form.
// Tail = two-level wait-free atomic combine (16-way spread -> 16 leaders ->
// 1 global), ~32 serialized RMW depth vs R5's ~512 (which cost ~10us).
// Counters self-heal from 0 / 0xAA poison via atomicDec wrap (R5-proven);
// float cells reset via atomicExch each call (replay-safe).

#define NATOMS 256
#define KOPS   16
#define NB     16

// Replicates jnp.mod(x, 1.0) (validated bit-exact in R1).
__device__ __forceinline__ float wrap01(float x) {
    float m = fmodf(x, 1.0f);
    if (m < 0.0f) m += 1.0f;
    return m;
}

__global__ __launch_bounds__(1024) void sgo_kernel(
    const float* __restrict__ fracs,
    const float* __restrict__ oprss,
    float* __restrict__ ws,          // workspace base (float view)
    float* __restrict__ out)
{
    const int blk = blockIdx.x;      // 0..255 = (b,k)
    const int b   = blk >> 4;
    const int k   = blk & 15;
    const int tid = threadIdx.x;     // 0..1023
    const int i   = tid & 127;       // pair index: atoms A=2i, B=2i+1
    const int c   = tid >> 7;        // t-chunk 0..7 (16 t's each)

    const float* f = fracs + (size_t)b * NATOMS * 3;

    // even/odd split arrays + 64-slot halo (slot 128+x duplicates x, x<64)
    __shared__ float4 idE[192], idO[192], opE[192], opO[192];

    if (tid < 512) {
        const int atom = tid & 255;
        float fx = f[atom*3+0], fy = f[atom*3+1], fz = f[atom*3+2];
        if (tid >= 256) {
            const float* op = oprss + (size_t)(b * KOPS + k) * 9;
            float gx = wrap01(fx*op[0] + fy*op[1] + fz*op[2]);
            float gy = wrap01(fx*op[3] + fy*op[4] + fz*op[5]);
            float gz = wrap01(fx*op[6] + fy*op[7] + fz*op[8]);
            fx = gx; fy = gy; fz = gz;
        }
        float4 v4 = make_float4(fx, fy, fz, 0.0f);
        float4* arrE = (tid < 256) ? idE : opE;
        float4* arrO = (tid < 256) ? idO : opO;
        const int slot = atom >> 1;
        if (atom & 1) arrO[slot] = v4; else arrE[slot] = v4;
        if (atom < 128) {
            if (atom & 1) arrO[128 + slot] = v4; else arrE[128 + slot] = v4;
        }
    }
    __syncthreads();

    const float4 ia = idE[i], ib = idO[i];   // identity atoms 2i, 2i+1
    const float4 oa = opE[i], ob = opO[i];   // op atoms 2i, 2i+1

    float i2x=0.f,i2y=0.f,i2z=0.f, i1x=0.f,i1y=0.f,i1z=0.f;  // identity w2/w1
    float o2x=0.f,o2y=0.f,o2z=0.f, o1x=0.f,o1y=0.f,o1z=0.f;  // op w2/w1

#define EVAL_INTO(FJ, S, AX, AY, AZ, SGN) do {                                 \
        float dx = (FJ).x - (S).x, dy = (FJ).y - (S).y, dz = (FJ).z - (S).z;   \
        float vx = dx - rintf(dx), vy = dy - rintf(dy), vz = dz - rintf(dz);   \
        float px = vx*vx, py = vy*vy, pz = vz*vz;                              \
        float d2 = px + py + pz;                                               \
        float m  = (d2 <= 0.16f) ? (SGN) : 0.0f;                               \
        AX = fmaf(px, m, AX); AY = fmaf(py, m, AY); AZ = fmaf(pz, m, AZ);      \
    } while (0)

    // chunk c covers t = 2+16c .. 17+16c; even t -> *E[i + t/2],
    // odd t -> *O[i + (t-1)/2]; both index = eb + u, eb = i + 1 + 8c.
    // One read serves eval(A) and eval(B) (R6-validated, absmax 0.0).
    const int eb = i + 1 + 8 * c;
    #pragma unroll
    for (int u = 0; u < 8; ++u) {
        {   const float4 fj = idE[eb + u];
            EVAL_INTO(fj, ia, i2x, i2y, i2z, 1.0f);
            EVAL_INTO(fj, ib, i2x, i2y, i2z, 1.0f);
        }
        {   const float4 fj = opE[eb + u];
            EVAL_INTO(fj, oa, o2x, o2y, o2z, 1.0f);
            EVAL_INTO(fj, ob, o2x, o2y, o2z, 1.0f);
        }
        {   const float4 fj = idO[eb + u];
            EVAL_INTO(fj, ia, i2x, i2y, i2z, 1.0f);
            EVAL_INTO(fj, ib, i2x, i2y, i2z, 1.0f);
        }
        {   const float4 fj = opO[eb + u];
            EVAL_INTO(fj, oa, o2x, o2y, o2z, 1.0f);
            EVAL_INTO(fj, ob, o2x, o2y, o2z, 1.0f);
        }
    }

    // epilogue (chunk 7 = the one whose range reached t=128,129):
    //  t=1  : pair {2i,2i+1}, weight 2, no read (partner already in regs)
    //  t=128: counted w2 in main; subtract one copy -> net weight 1
    //  t=129: likewise
    if (c == 7) {
        EVAL_INTO(ib, ia, i2x, i2y, i2z, 1.0f);
        EVAL_INTO(ob, oa, o2x, o2y, o2z, 1.0f);
        {   const float4 fj = idE[i + 64];
            EVAL_INTO(fj, ia, i1x, i1y, i1z, -1.0f);
            EVAL_INTO(fj, ib, i1x, i1y, i1z, -1.0f);
        }
        {   const float4 fj = opE[i + 64];
            EVAL_INTO(fj, oa, o1x, o1y, o1z, -1.0f);
            EVAL_INTO(fj, ob, o1x, o1y, o1z, -1.0f);
        }
        {   const float4 fj = idO[i + 64];
            EVAL_INTO(fj, ia, i1x, i1y, i1z, -1.0f);
            EVAL_INTO(fj, ib, i1x, i1y, i1z, -1.0f);
        }
        {   const float4 fj = opO[i + 64];
            EVAL_INTO(fj, oa, o1x, o1y, o1z, -1.0f);
            EVAL_INTO(fj, ob, o1x, o1y, o1z, -1.0f);
        }
    }
#undef EVAL_INTO

    // per-thread (s_k - s_0) contribution, then block reduce
    float dxr = fmaf(2.0f, o2x, o1x) - fmaf(2.0f, i2x, i1x);
    float dyr = fmaf(2.0f, o2y, o1y) - fmaf(2.0f, i2y, i1y);
    float dzr = fmaf(2.0f, o2z, o1z) - fmaf(2.0f, i2z, i1z);

    for (int off = 32; off >= 1; off >>= 1) {
        dxr += __shfl_xor(dxr, off);
        dyr += __shfl_xor(dyr, off);
        dzr += __shfl_xor(dzr, off);
    }
    __shared__ float part[16][3];
    const int wave = tid >> 6;
    if ((tid & 63) == 0) { part[wave][0] = dxr; part[wave][1] = dyr; part[wave][2] = dzr; }
    __syncthreads();

    if (tid == 0) {
        float sx = 0.f, sy = 0.f, sz = 0.f;
        #pragma unroll
        for (int w = 0; w < 16; ++w) {
            sx += part[w][0]; sy += part[w][1]; sz += part[w][2];
        }
        float v = sqrtf(sx*sx + sy*sy + sz*sz) * (1.0f / 256.0f);

        // ---- two-level wait-free combine ----
        // cells spread 256B apart; counters self-heal via atomicDec wrap
        float*        partial = ws + (size_t)b * 64;                 // level 1
        unsigned int* ctrb    = (unsigned int*)(ws + 1024 + b * 64);
        float*        gacc    = ws + 2048;                            // level 2
        unsigned int* gctr    = (unsigned int*)(ws + 2064);

        float old = atomicAdd(partial, v);
        asm volatile("" : : "v"(old) : "memory");   // add completed before dec
        unsigned int o = atomicDec(ctrb, 15u);      // 16th arrival sees old==1
        if (o == 1u) {
            float s = atomicExch(partial, 0.0f);    // full b-partial + reset
            asm volatile("" : : "v"(s) : "memory");
            float g = atomicAdd(gacc, s);
            asm volatile("" : : "v"(g) : "memory");
            unsigned int o2 = atomicDec(gctr, 15u); // 16th leader sees old==1
            if (o2 == 1u) {
                float total = atomicExch(gacc, 0.0f);  // full sum + reset
                out[0] = total;
            }
        }
    }
}

extern "C" void kernel_launch(void* const* d_in, const int* in_sizes, int n_in,
                              void* d_out, int out_size, void* d_ws, size_t ws_size,
                              hipStream_t stream) {
    const float* fracs = (const float*)d_in[0];
    const float* oprss = (const float*)d_in[2];
    float* out = (float*)d_out;
    float* ws  = (float*)d_ws;

    sgo_kernel<<<NB * KOPS, 1024, 0, stream>>>(fracs, oprss, ws, out);
}

// Round 8
// 14.460 us; speedup vs baseline: 1.1946x; 1.1946x over previous
//
#include <hip/hip_runtime.h>
#include <math.h>

// SGO_Loss_Prod: B=16, N=256 atoms, K=16 ops, r=0.4.
// Min-image collapse (r<0.5): at most one periodic shift passes the mask ->
// direct minimum-image eval (bit-exact, R1/R2). Even/odd register blocking +
// half-shell weight-2 with o=1..64 read-offsets (R6, absmax 0.0).
// R8: PERFECT BALANCE. 256 uniform blocks (1/CU) x 512 threads. Block (b,k)
// = full op task + 1/16 slice of b's identity task (id sharded over the b's
// 16 blocks, recombined in k2 -- sums are linear). No redundancy, no
// stragglers (R6's 544-block map left 32 CUs with 1.5x critical path).
// Two-kernel structure kept: fused atomic tails cost >=2.5us (R3/R5/R7).

#define NB   16
#define KOPS 16

// Replicates jnp.mod(x, 1.0) (validated bit-exact in R1).
__device__ __forceinline__ float wrap01(float x) {
    float m = fmodf(x, 1.0f);
    if (m < 0.0f) m += 1.0f;
    return m;
}

__global__ __launch_bounds__(512) void pair_kernel(
    const float* __restrict__ fracs,
    const float* __restrict__ oprss,
    float4* __restrict__ rows)       // [512]: op rows 0..255, id rows 256..511
{
    const int blk = blockIdx.x;      // 0..255 = (b,k)
    const int b   = blk >> 4;
    const int k   = blk & 15;
    const int tid = threadIdx.x;     // 0..511
    const int i   = tid & 127;       // pair index: atoms A=2i, B=2i+1
    const int c   = (tid >> 7) & 3;  // o-chunk 0..3

    const float* f = fracs + (size_t)b * 256 * 3;

    // even/odd split arrays + halo (slot 128+s duplicates slot s, s<64)
    __shared__ float4 idE[192], idO[192], opE[192], opO[192];

    {   // stage: tids 0..255 -> identity set, 256..511 -> op set
        const int atom = tid & 255;
        float fx = f[atom*3+0], fy = f[atom*3+1], fz = f[atom*3+2];
        if (tid >= 256) {
            const float* op = oprss + (size_t)(b * KOPS + k) * 9;
            float gx = wrap01(fx*op[0] + fy*op[1] + fz*op[2]);
            float gy = wrap01(fx*op[3] + fy*op[4] + fz*op[5]);
            float gz = wrap01(fx*op[6] + fy*op[7] + fz*op[8]);
            fx = gx; fy = gy; fz = gz;
        }
        float4 v4 = make_float4(fx, fy, fz, 0.0f);
        float4* arr = (tid < 256) ? ((atom & 1) ? idO : idE)
                                  : ((atom & 1) ? opO : opE);
        const int slot = atom >> 1;
        arr[slot] = v4;
        if (atom < 128) arr[128 + slot] = v4;
    }
    __syncthreads();

    const float4 ia = idE[i], ib = idO[i];   // identity atoms 2i, 2i+1
    const float4 oa = opE[i], ob = opO[i];   // op atoms 2i, 2i+1

    float o2x=0.f,o2y=0.f,o2z=0.f, o1x=0.f,o1y=0.f,o1z=0.f;  // op w2 / corr
    float i2x=0.f,i2y=0.f,i2z=0.f, i1x=0.f,i1y=0.f,i1z=0.f;  // id w2 / corr

#define EVAL_INTO(FJ, S, AX, AY, AZ, SGN) do {                                 \
        float dx = (FJ).x - (S).x, dy = (FJ).y - (S).y, dz = (FJ).z - (S).z;   \
        float vx = dx - rintf(dx), vy = dy - rintf(dy), vz = dz - rintf(dz);   \
        float px = vx*vx, py = vy*vy, pz = vz*vz;                              \
        float d2 = px + py + pz;                                               \
        float m  = (d2 <= 0.16f) ? (SGN) : 0.0f;                               \
        AX = fmaf(px, m, AX); AY = fmaf(py, m, AY); AZ = fmaf(pz, m, AZ);      \
    } while (0)

    // OP main: read-offsets o = 16c+1 .. 16c+16. Read E[i+o] covers A-side
    // t=2o & B-side t=2o-1; O[i+o] covers A-side t=2o+1 & B-side t=2o.
    // Union over o=1..64: A t=2..129, B t=1..128, each once, weight 2.
    {
        const int eb = i + 16 * c + 1;
        #pragma unroll
        for (int u = 0; u < 16; ++u) {
            {   const float4 fj = opE[eb + u];
                EVAL_INTO(fj, oa, o2x, o2y, o2z, 1.0f);
                EVAL_INTO(fj, ob, o2x, o2y, o2z, 1.0f);
            }
            {   const float4 fj = opO[eb + u];
                EVAL_INTO(fj, oa, o2x, o2y, o2z, 1.0f);
                EVAL_INTO(fj, ob, o2x, o2y, o2z, 1.0f);
            }
        }
    }
    // ID slice: this block's share is o = 4k+1 .. 4k+4; this thread does
    // o = 4k+1+c (one E read + one O read, 4 evals). Union over the b's 16
    // blocks x 4 chunks = o=1..64: the complete identity task, once.
    {
        const int ebi = i + 4 * k + 1 + c;
        {   const float4 fj = idE[ebi];
            EVAL_INTO(fj, ia, i2x, i2y, i2z, 1.0f);
            EVAL_INTO(fj, ib, i2x, i2y, i2z, 1.0f);
        }
        {   const float4 fj = idO[ebi];
            EVAL_INTO(fj, ia, i2x, i2y, i2z, 1.0f);
            EVAL_INTO(fj, ib, i2x, i2y, i2z, 1.0f);
        }
    }
    // Epilogue (R6-validated): +A-side t=1 (pair {2i,2i+1}, partner already
    // in regs); -one copy of the o=64 double-counts (A-128, B-127 from E;
    // A-129, B-128 from O). Op: every block; id: once per b (k==0 / k==15).
    if (c == 0) {
        EVAL_INTO(ob, oa, o2x, o2y, o2z, 1.0f);
        if (k == 0) EVAL_INTO(ib, ia, i2x, i2y, i2z, 1.0f);
    }
    if (c == 3) {
        {   const float4 fj = opE[i + 64];
            EVAL_INTO(fj, oa, o1x, o1y, o1z, -1.0f);
            EVAL_INTO(fj, ob, o1x, o1y, o1z, -1.0f);
        }
        {   const float4 fj = opO[i + 64];
            EVAL_INTO(fj, oa, o1x, o1y, o1z, -1.0f);
            EVAL_INTO(fj, ob, o1x, o1y, o1z, -1.0f);
        }
        if (k == 15) {
            {   const float4 fj = idE[i + 64];
                EVAL_INTO(fj, ia, i1x, i1y, i1z, -1.0f);
                EVAL_INTO(fj, ib, i1x, i1y, i1z, -1.0f);
            }
            {   const float4 fj = idO[i + 64];
                EVAL_INTO(fj, ia, i1x, i1y, i1z, -1.0f);
                EVAL_INTO(fj, ib, i1x, i1y, i1z, -1.0f);
            }
        }
    }
#undef EVAL_INTO

    // net task sums: 2*(weight-2 bank) + (correction bank, accumulated at -1)
    float sox = fmaf(2.0f, o2x, o1x);
    float soy = fmaf(2.0f, o2y, o1y);
    float soz = fmaf(2.0f, o2z, o1z);
    float six = fmaf(2.0f, i2x, i1x);
    float siy = fmaf(2.0f, i2y, i1y);
    float siz = fmaf(2.0f, i2z, i1z);

    // wave64 butterfly reduce (6 values)
    for (int off = 32; off >= 1; off >>= 1) {
        sox += __shfl_xor(sox, off);  soy += __shfl_xor(soy, off);
        soz += __shfl_xor(soz, off);  six += __shfl_xor(six, off);
        siy += __shfl_xor(siy, off);  siz += __shfl_xor(siz, off);
    }
    __shared__ float part[8][6];
    const int wave = tid >> 6;
    if ((tid & 63) == 0) {
        part[wave][0] = sox; part[wave][1] = soy; part[wave][2] = soz;
        part[wave][3] = six; part[wave][4] = siy; part[wave][5] = siz;
    }
    __syncthreads();
    if (tid == 0) {
        float r0=0.f,r1=0.f,r2=0.f,r3=0.f,r4=0.f,r5=0.f;
        #pragma unroll
        for (int w = 0; w < 8; ++w) {
            r0 += part[w][0]; r1 += part[w][1]; r2 += part[w][2];
            r3 += part[w][3]; r4 += part[w][4]; r5 += part[w][5];
        }
        rows[blk]       = make_float4(r0, r1, r2, 0.0f);   // op task sum
        rows[256 + blk] = make_float4(r3, r4, r5, 0.0f);   // id partial
    }
}

__global__ __launch_bounds__(256) void finish_kernel(
    const float4* __restrict__ rows, float* __restrict__ out)
{
    const int t = threadIdx.x;        // 0..255 -> (b,k)
    const int b = t >> 4;
    const float4 so = rows[t];        // op sum for (b,k)
    float six = 0.f, siy = 0.f, siz = 0.f;
    #pragma unroll
    for (int k2 = 0; k2 < 16; ++k2) { // identity = sum of b's 16 partials
        const float4 r = rows[256 + b * 16 + k2];
        six += r.x; siy += r.y; siz += r.z;
    }
    float d0 = so.x - six, d1 = so.y - siy, d2 = so.z - siz;
    float v = sqrtf(d0*d0 + d1*d1 + d2*d2);

    for (int off = 32; off >= 1; off >>= 1) v += __shfl_xor(v, off);
    __shared__ float part[4];
    if ((t & 63) == 0) part[t >> 6] = v;
    __syncthreads();
    if (t == 0) out[0] = (part[0] + part[1] + part[2] + part[3]) * (1.0f / 256.0f);
}

extern "C" void kernel_launch(void* const* d_in, const int* in_sizes, int n_in,
                              void* d_out, int out_size, void* d_ws, size_t ws_size,
                              hipStream_t stream) {
    const float* fracs = (const float*)d_in[0];
    const float* oprss = (const float*)d_in[2];
    float* out   = (float*)d_out;
    float4* rows = (float4*)d_ws;    // 512 * 16 B = 8 KB

    pair_kernel<<<NB * KOPS, 512, 0, stream>>>(fracs, oprss, rows);
    finish_kernel<<<1, 256, 0, stream>>>(rows, out);
}